// Round 1
// baseline (379.569 us; speedup 1.0000x reference)
//
#include <hip/hip_runtime.h>
#include <hip/hip_bf16.h>
#include <stdint.h>

// Problem constants (fixed by reference setup_inputs)
#define T_TOKENS 32768     // 32*1024
#define D_IN     768
#define D_OUT    256
#define N_EXP    8
#define S_TOT    (T_TOKENS*2)   // 65536 routed slots
#define S_PAD    66048          // 65536 + 8*64 worst-case per-expert 64-padding

typedef __attribute__((ext_vector_type(8))) short bf16x8;
typedef __attribute__((ext_vector_type(4))) float f32x4;

__device__ __forceinline__ unsigned short f2bf(float f) {
    unsigned u = __float_as_uint(f);
    unsigned r = (u + 0x7FFFu + ((u >> 16) & 1u)) >> 16;  // RNE
    return (unsigned short)r;
}

// ---------------- W fp32 [e][k][n] -> bf16 transposed [e][n][k] ----------------
__global__ void convw_kernel(const float* __restrict__ W, unsigned short* __restrict__ WT) {
    int idx = blockIdx.x * 256 + threadIdx.x;       // linear over e*768*256 + k*256 + n
    float v = W[idx];                                // coalesced read
    int n  = idx & 255;
    int ek = idx >> 8;                               // e*768 + k
    int k  = ek % D_IN;
    int e  = ek / D_IN;
    WT[(size_t)e * (D_IN * D_OUT) + (size_t)n * D_IN + k] = f2bf(v);
}

// ---------------- gating: fp32 logits, softmax, top-2 ----------------
__global__ void gate_kernel(const float* __restrict__ x,
                            const float* __restrict__ gW,
                            const float* __restrict__ gb,
                            float* __restrict__ topk_w,
                            int*   __restrict__ topk_e) {
    int wave = threadIdx.x >> 6;
    int lane = threadIdx.x & 63;
    int t = blockIdx.x * 4 + wave;                  // 1 token per wave
    const float* xr = x + (size_t)t * D_IN;
    float acc[8] = {0,0,0,0,0,0,0,0};
    for (int i = lane; i < D_IN; i += 64) {
        float xv = xr[i];                            // coalesced
        const float4* g4 = (const float4*)(gW + i * 8);
        float4 g0 = g4[0], g1 = g4[1];
        acc[0] += xv*g0.x; acc[1] += xv*g0.y; acc[2] += xv*g0.z; acc[3] += xv*g0.w;
        acc[4] += xv*g1.x; acc[5] += xv*g1.y; acc[6] += xv*g1.z; acc[7] += xv*g1.w;
    }
    #pragma unroll
    for (int m = 32; m; m >>= 1) {
        #pragma unroll
        for (int e = 0; e < 8; e++) acc[e] += __shfl_xor(acc[e], m, 64);
    }
    // every lane holds full logits now
    float mx = -1e30f;
    #pragma unroll
    for (int e = 0; e < 8; e++) { acc[e] += gb[e]; mx = fmaxf(mx, acc[e]); }
    float w[8]; float s = 0.f;
    #pragma unroll
    for (int e = 0; e < 8; e++) { w[e] = expf(acc[e] - mx); s += w[e]; }
    float inv = 1.0f / s;
    int e0 = 0; float b0 = -1.f;
    #pragma unroll
    for (int e = 0; e < 8; e++) if (w[e] > b0) { b0 = w[e]; e0 = e; }   // ties -> lowest idx
    int e1 = 0; float b1 = -1.f;
    #pragma unroll
    for (int e = 0; e < 8; e++) if (e != e0 && w[e] > b1) { b1 = w[e]; e1 = e; }
    if (lane == 0) {
        topk_w[t*2]   = b0 * inv;
        topk_w[t*2+1] = b1 * inv;
        topk_e[t*2]   = e0;
        topk_e[t*2+1] = e1;
    }
}

// ---------------- per-expert histogram (LDS-aggregated) ----------------
__global__ void count_kernel(const int* __restrict__ topk_e, int* __restrict__ counts) {
    __shared__ int h[8];
    if (threadIdx.x < 8) h[threadIdx.x] = 0;
    __syncthreads();
    int base = blockIdx.x * 256 * 8 + threadIdx.x;
    #pragma unroll
    for (int j = 0; j < 8; j++) atomicAdd(&h[topk_e[base + j * 256]], 1);
    __syncthreads();
    if (threadIdx.x < 8) atomicAdd(&counts[threadIdx.x], h[threadIdx.x]);
}

// ---------------- exclusive prefix, 64-aligned regions ----------------
__global__ void offsets_kernel(const int* __restrict__ counts, int* __restrict__ offs) {
    if (threadIdx.x == 0) {
        int o = 0; offs[0] = 0;
        for (int e = 0; e < 8; e++) { o += (counts[e] + 63) & ~63; offs[e+1] = o; }
    }
}

// ---------------- scatter (token,k) pairs into expert buckets ----------------
__global__ void scatter_kernel(const int* __restrict__ topk_e, const float* __restrict__ topk_w,
                               const int* __restrict__ offs, int* __restrict__ cursors,
                               int* __restrict__ slot_token, float* __restrict__ slot_w) {
    __shared__ int hcnt[8], hbase[8];
    if (threadIdx.x < 8) hcnt[threadIdx.x] = 0;
    __syncthreads();
    int idx[4], ee[4], lr[4];
    int base = blockIdx.x * 256 * 4 + threadIdx.x;
    #pragma unroll
    for (int j = 0; j < 4; j++) {
        idx[j] = base + j * 256;
        ee[j]  = topk_e[idx[j]];
        lr[j]  = atomicAdd(&hcnt[ee[j]], 1);         // LDS atomic: fast
    }
    __syncthreads();
    if (threadIdx.x < 8) hbase[threadIdx.x] = atomicAdd(&cursors[threadIdx.x], hcnt[threadIdx.x]);
    __syncthreads();
    #pragma unroll
    for (int j = 0; j < 4; j++) {
        int slot = offs[ee[j]] + hbase[ee[j]] + lr[j];
        slot_token[slot] = idx[j] >> 1;              // token id
        slot_w[slot]     = topk_w[idx[j]];
    }
}

// ---------------- out = w0*b[e0] + w1*b[e1] (before GEMM atomics) ----------------
__global__ void biasinit_kernel(const float* __restrict__ eb, const float* __restrict__ topk_w,
                                const int* __restrict__ topk_e, float* __restrict__ out) {
    int t = blockIdx.x, c = threadIdx.x;
    float w0 = topk_w[t*2], w1 = topk_w[t*2+1];
    int   e0 = topk_e[t*2], e1 = topk_e[t*2+1];
    out[(size_t)t * D_OUT + c] = w0 * eb[e0 * D_OUT + c] + w1 * eb[e1 * D_OUT + c];
}

// ---------------- routed GEMM: gathered A (bf16 on the fly) x WT[e], atomic epilogue ----
__global__ __launch_bounds__(256) void moe_gemm_kernel(
        const float* __restrict__ x, const unsigned short* __restrict__ WT,
        const int* __restrict__ offs, const int* __restrict__ slot_token,
        const float* __restrict__ slot_w, float* __restrict__ out) {
    // LDS row stride 40 shorts (=80B): breaks 64B-stride bank pattern (2-way max = free)
    __shared__ unsigned short A_lds[64 * 40];
    __shared__ unsigned short B_lds[64 * 40];
    int row0 = blockIdx.y * 64;
    if (row0 >= offs[8]) return;                     // uniform exit: beyond padded total
    int expert = 0;
    #pragma unroll
    for (int e = 0; e < 8; e++) if (row0 >= offs[e] && row0 < offs[e+1]) expert = e;

    int n0  = blockIdx.x * 64;
    int tid = threadIdx.x;
    int srow = tid >> 2;                              // staging row 0..63
    int kq   = (tid & 3) * 8;                         // k sub-offset 0/8/16/24
    int tok  = slot_token[row0 + srow];
    const float* xrow = x + (size_t)(tok < 0 ? 0 : tok) * D_IN;
    const unsigned short* wrow = WT + (size_t)expert * (D_IN * D_OUT) + (size_t)(n0 + srow) * D_IN;

    int wave = tid >> 6, lane = tid & 63;
    int lrow = lane & 15, lquad = lane >> 4;
    f32x4 acc[4] = {{0,0,0,0},{0,0,0,0},{0,0,0,0},{0,0,0,0}};

    for (int k0 = 0; k0 < D_IN; k0 += 32) {
        __syncthreads();
        uint4 pack = make_uint4(0,0,0,0);
        if (tok >= 0) {
            float4 v0 = *(const float4*)(xrow + k0 + kq);
            float4 v1 = *(const float4*)(xrow + k0 + kq + 4);
            pack.x = f2bf(v0.x) | ((unsigned)f2bf(v0.y) << 16);
            pack.y = f2bf(v0.z) | ((unsigned)f2bf(v0.w) << 16);
            pack.z = f2bf(v1.x) | ((unsigned)f2bf(v1.y) << 16);
            pack.w = f2bf(v1.z) | ((unsigned)f2bf(v1.w) << 16);
        }
        *(uint4*)&A_lds[srow * 40 + kq] = pack;
        *(uint4*)&B_lds[srow * 40 + kq] = *(const uint4*)(wrow + k0 + kq);
        __syncthreads();
        bf16x8 a = *(const bf16x8*)&A_lds[(wave * 16 + lrow) * 40 + lquad * 8];
        #pragma unroll
        for (int s = 0; s < 4; s++) {
            bf16x8 b = *(const bf16x8*)&B_lds[(s * 16 + lrow) * 40 + lquad * 8];
            acc[s] = __builtin_amdgcn_mfma_f32_16x16x32_bf16(a, b, acc[s], 0, 0, 0);
        }
    }
    // epilogue: D mapping col=lane&15, row=quad*4+reg  [guide §3, m89-verified]
    #pragma unroll
    for (int r = 0; r < 4; r++) {
        int slot = row0 + wave * 16 + lquad * 4 + r;
        int tk = slot_token[slot];
        if (tk < 0) continue;
        float wgt = slot_w[slot];
        #pragma unroll
        for (int s = 0; s < 4; s++) {
            int col = n0 + s * 16 + lrow;
            atomicAdd(out + (size_t)tk * D_OUT + col, wgt * acc[s][r]);
        }
    }
}

extern "C" void kernel_launch(void* const* d_in, const int* in_sizes, int n_in,
                              void* d_out, int out_size, void* d_ws, size_t ws_size,
                              hipStream_t stream) {
    const float* x  = (const float*)d_in[0];
    const float* gW = (const float*)d_in[1];
    const float* gb = (const float*)d_in[2];
    const float* eW = (const float*)d_in[3];
    const float* eb = (const float*)d_in[4];
    float* out = (float*)d_out;
    char* ws = (char*)d_ws;

    // ws layout (≈4.2 MB total)
    float* topk_w          = (float*)(ws + 0);          // 256 KB
    int*   topk_e          = (int*)  (ws + 262144);     // 256 KB
    int*   counts          = (int*)  (ws + 524288);     // 32 B
    int*   cursors         = (int*)  (ws + 524320);     // 32 B
    int*   offs            = (int*)  (ws + 524352);     // 9 ints
    int*   slot_token      = (int*)  (ws + 524416);     // 258 KB
    float* slot_w          = (float*)(ws + 788608);     // 258 KB
    unsigned short* WT     = (unsigned short*)(ws + 1052800); // 3 MB bf16 W^T

    hipMemsetAsync(ws + 524288, 0, 128, stream);                 // counts+cursors+offs
    hipMemsetAsync(slot_token, 0xFF, S_PAD * sizeof(int), stream); // all slots -> -1

    convw_kernel   <<<N_EXP * D_IN * D_OUT / 256, 256, 0, stream>>>(eW, WT);
    gate_kernel    <<<T_TOKENS / 4, 256, 0, stream>>>(x, gW, gb, topk_w, topk_e);
    count_kernel   <<<S_TOT / (256 * 8), 256, 0, stream>>>(topk_e, counts);
    offsets_kernel <<<1, 64, 0, stream>>>(counts, offs);
    scatter_kernel <<<S_TOT / (256 * 4), 256, 0, stream>>>(topk_e, topk_w, offs, cursors,
                                                           slot_token, slot_w);
    biasinit_kernel<<<T_TOKENS, D_OUT, 0, stream>>>(eb, topk_w, topk_e, out);
    dim3 ggrid(D_OUT / 64, S_PAD / 64);   // 4 x 1032
    moe_gemm_kernel<<<ggrid, 256, 0, stream>>>(x, WT, offs, slot_token, slot_w, out);
}

// Round 2
// 348.409 us; speedup vs baseline: 1.0894x; 1.0894x over previous
//
#include <hip/hip_runtime.h>
#include <hip/hip_bf16.h>
#include <stdint.h>

// Problem constants (fixed by reference setup_inputs)
#define T_TOKENS 32768     // 32*1024
#define D_IN     768
#define D_OUT    256
#define N_EXP    8
#define S_TOT    (T_TOKENS*2)   // 65536 routed slots
#define S_PAD    66048          // 65536 + 8*64 worst-case per-expert 64-padding

typedef __attribute__((ext_vector_type(8))) short bf16x8;
typedef __attribute__((ext_vector_type(4))) float f32x4;

__device__ __forceinline__ unsigned short f2bf(float f) {
    unsigned u = __float_as_uint(f);
    unsigned r = (u + 0x7FFFu + ((u >> 16) & 1u)) >> 16;  // RNE
    return (unsigned short)r;
}

// async global->LDS, 16B per lane. LDS dest must be wave-uniform-base + lane*16.
__device__ __forceinline__ void async16(void* lds, const void* g) {
    __builtin_amdgcn_global_load_lds(
        (const __attribute__((address_space(1))) unsigned int*)g,
        (__attribute__((address_space(3))) unsigned int*)lds, 16, 0, 0);
}

// ---------------- W fp32 [e][k][n] -> bf16 transposed [e][n][k] ----------------
__global__ void convw_kernel(const float* __restrict__ W, unsigned short* __restrict__ WT) {
    int idx = blockIdx.x * 256 + threadIdx.x;       // linear over e*768*256 + k*256 + n
    float v = W[idx];                                // coalesced read
    int n  = idx & 255;
    int ek = idx >> 8;                               // e*768 + k
    int k  = ek % D_IN;
    int e  = ek / D_IN;
    WT[(size_t)e * (D_IN * D_OUT) + (size_t)n * D_IN + k] = f2bf(v);
}

// ------- gating: fp32 logits, softmax, top-2; also emits x as bf16 (fused) -------
__global__ void gate_kernel(const float* __restrict__ x,
                            const float* __restrict__ gW,
                            const float* __restrict__ gb,
                            unsigned short* __restrict__ xbf,   // may be null
                            float* __restrict__ topk_w,
                            int*   __restrict__ topk_e) {
    int wave = threadIdx.x >> 6;
    int lane = threadIdx.x & 63;
    int t = blockIdx.x * 4 + wave;                  // 1 token per wave
    const float* xr = x + (size_t)t * D_IN;
    float acc[8] = {0,0,0,0,0,0,0,0};
    #pragma unroll
    for (int j = 0; j < 3; j++) {
        int i = j * 256 + lane * 4;
        float4 xv = *(const float4*)(xr + i);
        if (xbf) {                                   // fused fp32->bf16 conversion of x
            uint2 p;
            p.x = f2bf(xv.x) | ((unsigned)f2bf(xv.y) << 16);
            p.y = f2bf(xv.z) | ((unsigned)f2bf(xv.w) << 16);
            *(uint2*)(xbf + (size_t)t * D_IN + i) = p;
        }
        float xs[4] = {xv.x, xv.y, xv.z, xv.w};
        #pragma unroll
        for (int r = 0; r < 4; r++) {
            const float4* g4 = (const float4*)(gW + (size_t)(i + r) * 8);
            float4 g0 = g4[0], g1 = g4[1];
            acc[0] += xs[r]*g0.x; acc[1] += xs[r]*g0.y; acc[2] += xs[r]*g0.z; acc[3] += xs[r]*g0.w;
            acc[4] += xs[r]*g1.x; acc[5] += xs[r]*g1.y; acc[6] += xs[r]*g1.z; acc[7] += xs[r]*g1.w;
        }
    }
    #pragma unroll
    for (int m = 32; m; m >>= 1) {
        #pragma unroll
        for (int e = 0; e < 8; e++) acc[e] += __shfl_xor(acc[e], m, 64);
    }
    float mx = -1e30f;
    #pragma unroll
    for (int e = 0; e < 8; e++) { acc[e] += gb[e]; mx = fmaxf(mx, acc[e]); }
    float w[8]; float s = 0.f;
    #pragma unroll
    for (int e = 0; e < 8; e++) { w[e] = expf(acc[e] - mx); s += w[e]; }
    float inv = 1.0f / s;
    int e0 = 0; float b0 = -1.f;
    #pragma unroll
    for (int e = 0; e < 8; e++) if (w[e] > b0) { b0 = w[e]; e0 = e; }   // ties -> lowest idx
    int e1 = 0; float b1 = -1.f;
    #pragma unroll
    for (int e = 0; e < 8; e++) if (e != e0 && w[e] > b1) { b1 = w[e]; e1 = e; }
    if (lane == 0) {
        topk_w[t*2]   = b0 * inv;
        topk_w[t*2+1] = b1 * inv;
        topk_e[t*2]   = e0;
        topk_e[t*2+1] = e1;
    }
}

// ---------------- per-expert histogram (LDS-aggregated) ----------------
__global__ void count_kernel(const int* __restrict__ topk_e, int* __restrict__ counts) {
    __shared__ int h[8];
    if (threadIdx.x < 8) h[threadIdx.x] = 0;
    __syncthreads();
    int base = blockIdx.x * 256 * 8 + threadIdx.x;
    #pragma unroll
    for (int j = 0; j < 8; j++) atomicAdd(&h[topk_e[base + j * 256]], 1);
    __syncthreads();
    if (threadIdx.x < 8) atomicAdd(&counts[threadIdx.x], h[threadIdx.x]);
}

// ---------------- scatter (token,w) into expert buckets; offsets computed locally ----
__global__ void scatter_kernel(const int* __restrict__ topk_e, const float* __restrict__ topk_w,
                               const int* __restrict__ counts, int* __restrict__ cursors,
                               int* __restrict__ slot_token, float* __restrict__ slot_w) {
    int offs[9]; offs[0] = 0;
    #pragma unroll
    for (int e = 0; e < 8; e++) offs[e+1] = offs[e] + ((counts[e] + 63) & ~63);
    __shared__ int hcnt[8], hbase[8];
    if (threadIdx.x < 8) hcnt[threadIdx.x] = 0;
    __syncthreads();
    int idx[4], ee[4], lr[4];
    int base = blockIdx.x * 256 * 4 + threadIdx.x;
    #pragma unroll
    for (int j = 0; j < 4; j++) {
        idx[j] = base + j * 256;
        ee[j]  = topk_e[idx[j]];
        lr[j]  = atomicAdd(&hcnt[ee[j]], 1);         // LDS atomic: fast
    }
    __syncthreads();
    if (threadIdx.x < 8) hbase[threadIdx.x] = atomicAdd(&cursors[threadIdx.x], hcnt[threadIdx.x]);
    __syncthreads();
    #pragma unroll
    for (int j = 0; j < 4; j++) {
        int slot = offs[ee[j]] + hbase[ee[j]] + lr[j];
        slot_token[slot] = idx[j] >> 1;              // token id
        slot_w[slot]     = topk_w[idx[j]];
    }
}

// ---- routed GEMM: 64 slots x 256 cols per block, BK=32, bias fused, atomic combine ----
// LDS layout: rows of 32 shorts (64B), 4x16B chunks, chunk-rotated: phys=(c+(r>>1))&3.
template<bool BF16A>
__global__ __launch_bounds__(256, 4) void moe_gemm_kernel(
        const float* __restrict__ x, const unsigned short* __restrict__ xbf,
        const unsigned short* __restrict__ WT, const float* __restrict__ eb,
        const int* __restrict__ counts, const int* __restrict__ slot_token,
        const float* __restrict__ slot_w, float* __restrict__ out) {
    __shared__ unsigned short A_lds[64 * 32];        // 4 KB
    __shared__ unsigned short B_lds[256 * 32];       // 16 KB

    int offs[9]; offs[0] = 0;
    #pragma unroll
    for (int e = 0; e < 8; e++) offs[e+1] = offs[e] + ((counts[e] + 63) & ~63);
    int row0 = blockIdx.x * 64;
    if (row0 >= offs[8]) return;                     // uniform exit
    int expert = 0;
    #pragma unroll
    for (int e = 0; e < 8; e++) if (row0 >= offs[e]) expert = e;

    int tid  = threadIdx.x;
    int wave = tid >> 6, lane = tid & 63;
    int lrow = lane & 15, lquad = lane >> 4;

    // ---- staging source addresses (LDS dest is linear-by-thread; swizzle the SOURCE) ----
    int srow = tid >> 2;                             // phys row this thread stages (A)
    int pch  = tid & 3;                              // phys 16B chunk within row
    int lc_a = (pch - (srow >> 1)) & 3;              // logical k-chunk stored at phys pch
    int tokA = slot_token[row0 + srow];
    size_t arow_off = (size_t)(tokA < 0 ? 0 : tokA) * D_IN;
    const unsigned short* abase = xbf + arow_off + lc_a * 8;
    const float*          afbase = x + arow_off + lc_a * 8;

    const unsigned short* bb = WT + (size_t)expert * (D_IN * D_OUT);
    const unsigned short* bsrc[4];
    #pragma unroll
    for (int i = 0; i < 4; i++) {
        int ci = i * 256 + tid;                      // phys 16B chunk index in B tile
        int br = ci >> 2, bp = ci & 3;
        int lc = (bp - (br >> 1)) & 3;
        bsrc[i] = bb + (size_t)br * D_IN + lc * 8;
    }

    // ---- frag LDS addresses (constant across K) ----
    const unsigned short* a_rd[4];
    const unsigned short* b_rd[4];
    #pragma unroll
    for (int m = 0; m < 4; m++) {
        int r = m * 16 + lrow;
        a_rd[m] = &A_lds[r * 32 + (((lquad + (r >> 1)) & 3)) * 8];
    }
    #pragma unroll
    for (int s = 0; s < 4; s++) {
        int r = wave * 64 + s * 16 + lrow;
        b_rd[s] = &B_lds[r * 32 + (((lquad + (r >> 1)) & 3)) * 8];
    }

    f32x4 acc[4][4];
    #pragma unroll
    for (int m = 0; m < 4; m++)
        #pragma unroll
        for (int s = 0; s < 4; s++) acc[m][s] = (f32x4){0,0,0,0};

    for (int k0 = 0; k0 < D_IN; k0 += 32) {
        if constexpr (BF16A) {
            async16(&A_lds[tid * 8], abase + k0);
        } else {
            float4 v0 = *(const float4*)(afbase + k0);
            float4 v1 = *(const float4*)(afbase + k0 + 4);
            uint4 pk;
            pk.x = f2bf(v0.x) | ((unsigned)f2bf(v0.y) << 16);
            pk.y = f2bf(v0.z) | ((unsigned)f2bf(v0.w) << 16);
            pk.z = f2bf(v1.x) | ((unsigned)f2bf(v1.y) << 16);
            pk.w = f2bf(v1.z) | ((unsigned)f2bf(v1.w) << 16);
            *(uint4*)&A_lds[tid * 8] = pk;
        }
        #pragma unroll
        for (int i = 0; i < 4; i++) async16(&B_lds[(i * 256 + tid) * 8], bsrc[i] + k0);
        __syncthreads();                             // drains vmcnt+lgkmcnt
        bf16x8 a[4];
        #pragma unroll
        for (int m = 0; m < 4; m++) a[m] = *(const bf16x8*)a_rd[m];
        #pragma unroll
        for (int s = 0; s < 4; s++) {
            bf16x8 b = *(const bf16x8*)b_rd[s];
            #pragma unroll
            for (int m = 0; m < 4; m++)
                acc[m][s] = __builtin_amdgcn_mfma_f32_16x16x32_bf16(a[m], b, acc[m][s], 0, 0, 0);
        }
        __syncthreads();                             // LDS reuse next step
    }

    // epilogue: D mapping col=lane&15, row=quad*4+reg; bias fused, weighted atomic combine
    float bias_s[4];
    #pragma unroll
    for (int s = 0; s < 4; s++) bias_s[s] = eb[expert * D_OUT + wave * 64 + s * 16 + lrow];
    #pragma unroll
    for (int m = 0; m < 4; m++) {
        #pragma unroll
        for (int r = 0; r < 4; r++) {
            int slot = row0 + m * 16 + lquad * 4 + r;
            int tk = slot_token[slot];
            if (tk < 0) continue;
            float wgt = slot_w[slot];
            #pragma unroll
            for (int s = 0; s < 4; s++) {
                int col = wave * 64 + s * 16 + lrow;
                atomicAdd(out + (size_t)tk * D_OUT + col, wgt * (acc[m][s][r] + bias_s[s]));
            }
        }
    }
}

extern "C" void kernel_launch(void* const* d_in, const int* in_sizes, int n_in,
                              void* d_out, int out_size, void* d_ws, size_t ws_size,
                              hipStream_t stream) {
    const float* x  = (const float*)d_in[0];
    const float* gW = (const float*)d_in[1];
    const float* gb = (const float*)d_in[2];
    const float* eW = (const float*)d_in[3];
    const float* eb = (const float*)d_in[4];
    float* out = (float*)d_out;
    char* ws = (char*)d_ws;

    // ws layout
    float* topk_w      = (float*)(ws + 0);            // 256 KB
    int*   topk_e      = (int*)  (ws + 262144);       // 256 KB
    int*   counts      = (int*)  (ws + 524288);       // 32 B
    int*   cursors     = (int*)  (ws + 524320);       // 32 B
    int*   slot_token  = (int*)  (ws + 524416);       // 258 KB (S_PAD)
    float* slot_w      = (float*)(ws + 788608);       // 258 KB
    unsigned short* WT = (unsigned short*)(ws + 1052800);  // 3 MB bf16 W^T
    unsigned short* xbf= (unsigned short*)(ws + 4198528);  // 48 MB bf16 x
    const size_t NEED  = 4198528 + (size_t)T_TOKENS * D_IN * 2;
    bool bf16a = (ws_size >= NEED);

    hipMemsetAsync(ws + 524288, 0, 128, stream);                   // counts+cursors
    hipMemsetAsync(slot_token, 0xFF, S_PAD * sizeof(int), stream); // all slots -> -1
    hipMemsetAsync(out, 0, (size_t)out_size * sizeof(float), stream); // bias added in epilogue

    convw_kernel  <<<N_EXP * D_IN * D_OUT / 256, 256, 0, stream>>>(eW, WT);
    gate_kernel   <<<T_TOKENS / 4, 256, 0, stream>>>(x, gW, gb, bf16a ? xbf : nullptr,
                                                     topk_w, topk_e);
    count_kernel  <<<S_TOT / (256 * 8), 256, 0, stream>>>(topk_e, counts);
    scatter_kernel<<<S_TOT / (256 * 4), 256, 0, stream>>>(topk_e, topk_w, counts, cursors,
                                                          slot_token, slot_w);
    if (bf16a) {
        moe_gemm_kernel<true><<<S_PAD / 64, 256, 0, stream>>>(x, xbf, WT, eb, counts,
                                                              slot_token, slot_w, out);
    } else {
        moe_gemm_kernel<false><<<S_PAD / 64, 256, 0, stream>>>(x, xbf, WT, eb, counts,
                                                               slot_token, slot_w, out);
    }
}

// Round 3
// 310.895 us; speedup vs baseline: 1.2209x; 1.1207x over previous
//
#include <hip/hip_runtime.h>
#include <hip/hip_bf16.h>
#include <stdint.h>

// Problem constants (fixed by reference setup_inputs)
#define T_TOKENS 32768     // 32*1024
#define D_IN     768
#define D_OUT    256
#define N_EXP    8
#define S_TOT    (T_TOKENS*2)   // 65536 routed slots
#define S_PAD    66048          // 65536 + 8*64 worst-case per-expert 64-padding

typedef __attribute__((ext_vector_type(8))) short bf16x8;
typedef __attribute__((ext_vector_type(4))) float f32x4;

__device__ __forceinline__ unsigned short f2bf(float f) {
    unsigned u = __float_as_uint(f);
    return (unsigned short)((u + 0x7FFFu + ((u >> 16) & 1u)) >> 16);  // RNE
}
__device__ __forceinline__ unsigned pack_bf2(float a, float b) {
    return (unsigned)f2bf(a) | ((unsigned)f2bf(b) << 16);
}

// async global->LDS, 16B per lane. LDS dest must be wave-uniform base + lane*16.
__device__ __forceinline__ void async16(void* lds, const void* g) {
    __builtin_amdgcn_global_load_lds(
        (const __attribute__((address_space(1))) unsigned int*)g,
        (__attribute__((address_space(3))) unsigned int*)lds, 16, 0, 0);
}

// ---------------- W fp32 [e][k][n] -> bf16 transposed [e][n][k] ----------------
__global__ void convw_kernel(const float* __restrict__ W, unsigned short* __restrict__ WT) {
    int idx = blockIdx.x * 256 + threadIdx.x;
    float v = W[idx];                                // coalesced read
    int n  = idx & 255;
    int ek = idx >> 8;                               // e*768 + k
    int k  = ek % D_IN;
    int e  = ek / D_IN;
    WT[(size_t)e * (D_IN * D_OUT) + (size_t)n * D_IN + k] = f2bf(v);
}

// ------- gate: thread-per-token via LDS transpose; fuses xbf convert + histogram -----
// 1 wave per block, 64 tokens. x-tile 64x64 fp32 stride-65 (conflict-free both sides).
// gW reads are wave-uniform -> scalar/constant-cache broadcast (no VMEM scatter).
__global__ __launch_bounds__(64) void gate2_kernel(
        const float* __restrict__ x, const float* __restrict__ gW,
        const float* __restrict__ gb, unsigned short* __restrict__ xbf,
        float* __restrict__ topk_w, int* __restrict__ topk_e,
        int* __restrict__ counts) {
    __shared__ float tile[64 * 65];
    __shared__ int h[8];
    int tid = threadIdx.x;
    if (tid < 8) h[tid] = 0;
    int t0  = blockIdx.x * 64;
    int c16 = tid & 15, rb = tid >> 4;
    float acc[8] = {0,0,0,0,0,0,0,0};
    for (int kc = 0; kc < D_IN; kc += 64) {
        #pragma unroll
        for (int i = 0; i < 16; i++) {
            int row = i * 4 + rb;
            size_t g = (size_t)(t0 + row) * D_IN + kc + c16 * 4;
            float4 v = *(const float4*)(x + g);
            uint2 p; p.x = pack_bf2(v.x, v.y); p.y = pack_bf2(v.z, v.w);
            *(uint2*)(xbf + g) = p;                  // fused bf16 emit (coalesced 8B)
            float* d = &tile[row * 65 + c16 * 4];
            d[0] = v.x; d[1] = v.y; d[2] = v.z; d[3] = v.w;  // bank (4r+4c+j)%32: 2-way, free
        }
        __syncthreads();
        const float* gr = gW + (size_t)kc * 8;       // wave-uniform -> s_load
        #pragma unroll 8
        for (int kk = 0; kk < 64; kk++) {
            float xv = tile[tid * 65 + kk];          // bank (t+kk)%32: conflict-free
            #pragma unroll
            for (int e = 0; e < 8; e++) acc[e] += xv * gr[kk * 8 + e];
        }
        __syncthreads();
    }
    float mx = -1e30f;
    #pragma unroll
    for (int e = 0; e < 8; e++) { acc[e] += gb[e]; mx = fmaxf(mx, acc[e]); }
    float w[8], s = 0.f;
    #pragma unroll
    for (int e = 0; e < 8; e++) { w[e] = expf(acc[e] - mx); s += w[e]; }
    float inv = 1.0f / s;
    int e0 = 0; float b0 = -1.f;
    #pragma unroll
    for (int e = 0; e < 8; e++) if (w[e] > b0) { b0 = w[e]; e0 = e; }   // ties -> lowest idx
    int e1 = 0; float b1 = -1.f;
    #pragma unroll
    for (int e = 0; e < 8; e++) if (e != e0 && w[e] > b1) { b1 = w[e]; e1 = e; }
    int t = t0 + tid;
    topk_w[t*2]   = b0 * inv;
    topk_w[t*2+1] = b1 * inv;
    topk_e[t*2]   = e0;
    topk_e[t*2+1] = e1;
    atomicAdd(&h[e0], 1); atomicAdd(&h[e1], 1);
    __syncthreads();
    if (tid < 8) atomicAdd(&counts[tid], h[tid]);
}

// ---- scatter (token,w) into expert buckets + inverse map; offsets computed locally ----
__global__ void scatter_kernel(const int* __restrict__ topk_e, const float* __restrict__ topk_w,
                               const int* __restrict__ counts, int* __restrict__ cursors,
                               int* __restrict__ slot_token, float* __restrict__ slot_w,
                               int* __restrict__ inv_slot) {
    int offs[9]; offs[0] = 0;
    #pragma unroll
    for (int e = 0; e < 8; e++) offs[e+1] = offs[e] + ((counts[e] + 63) & ~63);
    __shared__ int hcnt[8], hbase[8];
    if (threadIdx.x < 8) hcnt[threadIdx.x] = 0;
    __syncthreads();
    int idx[4], ee[4], lr[4];
    int base = blockIdx.x * 256 * 4 + threadIdx.x;
    #pragma unroll
    for (int j = 0; j < 4; j++) {
        idx[j] = base + j * 256;
        ee[j]  = topk_e[idx[j]];
        lr[j]  = atomicAdd(&hcnt[ee[j]], 1);
    }
    __syncthreads();
    if (threadIdx.x < 8) hbase[threadIdx.x] = atomicAdd(&cursors[threadIdx.x], hcnt[threadIdx.x]);
    __syncthreads();
    #pragma unroll
    for (int j = 0; j < 4; j++) {
        int slot = offs[ee[j]] + hbase[ee[j]] + lr[j];
        slot_token[slot] = idx[j] >> 1;
        slot_w[slot]     = topk_w[idx[j]];
        inv_slot[idx[j]] = slot;
    }
}

// ---- routed GEMM: 64 slots x 256 cols/block, BK=32, LDS double-buffered, bias fused ---
// ROUTED: plain stores of (acc+bias) into routed[slot][col]; else atomic fallback.
template<bool ROUTED>
__global__ __launch_bounds__(256, 4) void moe_gemm_kernel(
        const unsigned short* __restrict__ xbf, const unsigned short* __restrict__ WT,
        const float* __restrict__ eb, const int* __restrict__ counts,
        const int* __restrict__ slot_token, const float* __restrict__ slot_w,
        float* __restrict__ dst) {
    __shared__ unsigned short A_lds[2][64 * 32];     // 2 x 4 KB
    __shared__ unsigned short B_lds[2][256 * 32];    // 2 x 16 KB

    int offs[9]; offs[0] = 0;
    #pragma unroll
    for (int e = 0; e < 8; e++) offs[e+1] = offs[e] + ((counts[e] + 63) & ~63);
    int row0 = blockIdx.x * 64;
    if (row0 >= offs[8]) return;                     // uniform exit
    int expert = 0;
    #pragma unroll
    for (int e = 0; e < 8; e++) if (row0 >= offs[e]) expert = e;

    int tid  = threadIdx.x;
    int wave = tid >> 6, lane = tid & 63;
    int lrow = lane & 15, lquad = lane >> 4;

    // staging source addresses (LDS dest linear-by-thread; chunk-rotate the SOURCE)
    int srow = tid >> 2;                             // A phys row
    int pch  = tid & 3;                              // phys 16B chunk
    int lc_a = (pch - (srow >> 1)) & 3;              // logical chunk at this phys slot
    int tokA = slot_token[row0 + srow];              // pad slots are 0 (valid row)
    const unsigned short* abase = xbf + (size_t)tokA * D_IN + lc_a * 8;

    const unsigned short* bb = WT + (size_t)expert * (D_IN * D_OUT);
    const unsigned short* bsrc[4];
    #pragma unroll
    for (int i = 0; i < 4; i++) {
        int ci = i * 256 + tid;
        int br = ci >> 2, bp = ci & 3;
        int lc = (bp - (br >> 1)) & 3;
        bsrc[i] = bb + (size_t)br * D_IN + lc * 8;
    }

    // frag LDS offsets (shorts), constant across K
    int a_off[4], b_off[4];
    #pragma unroll
    for (int m = 0; m < 4; m++) {
        int r = m * 16 + lrow;
        a_off[m] = r * 32 + ((lquad + (r >> 1)) & 3) * 8;
    }
    #pragma unroll
    for (int s = 0; s < 4; s++) {
        int r = wave * 64 + s * 16 + lrow;
        b_off[s] = r * 32 + ((lquad + (r >> 1)) & 3) * 8;
    }

    f32x4 acc[4][4];
    #pragma unroll
    for (int m = 0; m < 4; m++)
        #pragma unroll
        for (int s = 0; s < 4; s++) acc[m][s] = (f32x4){0,0,0,0};

    auto stage = [&](int k0, int p) {
        async16(&A_lds[p][tid * 8], abase + k0);
        #pragma unroll
        for (int i = 0; i < 4; i++) async16(&B_lds[p][(i * 256 + tid) * 8], bsrc[i] + k0);
    };

    stage(0, 0);
    #pragma unroll 1
    for (int s = 0; s < D_IN / 32; s++) {
        __syncthreads();                             // drains vmcnt: buf (s&1) ready
        if (s < D_IN / 32 - 1) stage((s + 1) * 32, (s + 1) & 1);  // overlap with MFMA below
        int p = s & 1;
        bf16x8 a[4];
        #pragma unroll
        for (int m = 0; m < 4; m++) a[m] = *(const bf16x8*)&A_lds[p][a_off[m]];
        #pragma unroll
        for (int q = 0; q < 4; q++) {
            bf16x8 b = *(const bf16x8*)&B_lds[p][b_off[q]];
            #pragma unroll
            for (int m = 0; m < 4; m++)
                acc[m][q] = __builtin_amdgcn_mfma_f32_16x16x32_bf16(a[m], b, acc[m][q], 0, 0, 0);
        }
    }

    // epilogue: D mapping col=lane&15, row=quad*4+reg
    float bias_s[4];
    #pragma unroll
    for (int q = 0; q < 4; q++) bias_s[q] = eb[expert * D_OUT + wave * 64 + q * 16 + lrow];
    #pragma unroll
    for (int m = 0; m < 4; m++) {
        #pragma unroll
        for (int r = 0; r < 4; r++) {
            int slot = row0 + m * 16 + lquad * 4 + r;
            if constexpr (ROUTED) {
                float* drow = dst + (size_t)slot * D_OUT;
                #pragma unroll
                for (int q = 0; q < 4; q++)
                    drow[wave * 64 + q * 16 + lrow] = acc[m][q][r] + bias_s[q];
            } else {
                int tk = slot_token[slot];
                float wgt = slot_w[slot];            // pads have wgt=0
                #pragma unroll
                for (int q = 0; q < 4; q++)
                    atomicAdd(dst + (size_t)tk * D_OUT + wave * 64 + q * 16 + lrow,
                              wgt * (acc[m][q][r] + bias_s[q]));
            }
        }
    }
}

// ---------------- combine: out[t] = w0*routed[s0] + w1*routed[s1] ----------------
__global__ void combine_kernel(const float* __restrict__ routed, const int* __restrict__ inv_slot,
                               const float* __restrict__ topk_w, float* __restrict__ out) {
    int flat = blockIdx.x * 256 + threadIdx.x;       // float4 index
    int t = flat >> 6, c = (flat & 63) * 4;
    int   s0 = inv_slot[t*2], s1 = inv_slot[t*2+1];
    float w0 = topk_w[t*2],   w1 = topk_w[t*2+1];
    float4 r0 = *(const float4*)(routed + (size_t)s0 * D_OUT + c);
    float4 r1 = *(const float4*)(routed + (size_t)s1 * D_OUT + c);
    float4 o;
    o.x = w0*r0.x + w1*r1.x; o.y = w0*r0.y + w1*r1.y;
    o.z = w0*r0.z + w1*r1.z; o.w = w0*r0.w + w1*r1.w;
    *(float4*)(out + (size_t)t * D_OUT + c) = o;
}

extern "C" void kernel_launch(void* const* d_in, const int* in_sizes, int n_in,
                              void* d_out, int out_size, void* d_ws, size_t ws_size,
                              hipStream_t stream) {
    const float* x  = (const float*)d_in[0];
    const float* gW = (const float*)d_in[1];
    const float* gb = (const float*)d_in[2];
    const float* eW = (const float*)d_in[3];
    const float* eb = (const float*)d_in[4];
    float* out = (float*)d_out;
    char* ws = (char*)d_ws;

    // ws layout
    float* topk_w      = (float*)(ws + 0);                 // 256 KB
    int*   topk_e      = (int*)  (ws + 262144);            // 256 KB
    int*   counts      = (int*)  (ws + 524288);            // 32 B
    int*   cursors     = (int*)  (ws + 524320);            // 32 B
    int*   slot_token  = (int*)  (ws + 524416);            // 264192 B (S_PAD)
    float* slot_w      = (float*)(ws + 788608);            // 264192 B (S_PAD)
    int*   inv_slot    = (int*)  (ws + 1052800);           // 262144 B (S_TOT)
    unsigned short* WT = (unsigned short*)(ws + 1314944);  // 3 MB bf16 W^T
    unsigned short* xbf= (unsigned short*)(ws + 4460672);  // 48 MB bf16 x
    float* routed      = (float*)(ws + 54792320);          // 67.6 MB routed outputs
    const size_t NEED_ROUTED = 54792320 + (size_t)S_PAD * D_OUT * 4;  // ~117 MB
    bool use_routed = (ws_size >= NEED_ROUTED);

    hipMemsetAsync(ws + 524288, 0, 128, stream);            // counts + cursors
    hipMemsetAsync(slot_token, 0, 528384, stream);          // slot_token + slot_w -> 0

    convw_kernel  <<<N_EXP * D_IN * D_OUT / 256, 256, 0, stream>>>(eW, WT);
    gate2_kernel  <<<T_TOKENS / 64, 64, 0, stream>>>(x, gW, gb, xbf, topk_w, topk_e, counts);
    scatter_kernel<<<S_TOT / (256 * 4), 256, 0, stream>>>(topk_e, topk_w, counts, cursors,
                                                          slot_token, slot_w, inv_slot);
    if (use_routed) {
        moe_gemm_kernel<true><<<S_PAD / 64, 256, 0, stream>>>(xbf, WT, eb, counts,
                                                              slot_token, slot_w, routed);
        combine_kernel<<<T_TOKENS * D_OUT / 4 / 256, 256, 0, stream>>>(routed, inv_slot,
                                                                       topk_w, out);
    } else {
        hipMemsetAsync(out, 0, (size_t)out_size * sizeof(float), stream);
        moe_gemm_kernel<false><<<S_PAD / 64, 256, 0, stream>>>(xbf, WT, eb, counts,
                                                               slot_token, slot_w, out);
    }
}

// Round 4
// 274.218 us; speedup vs baseline: 1.3842x; 1.1337x over previous
//
#include <hip/hip_runtime.h>
#include <hip/hip_bf16.h>
#include <stdint.h>

// Problem constants (fixed by reference setup_inputs)
#define T_TOKENS 32768     // 32*1024
#define D_IN     768
#define D_OUT    256
#define N_EXP    8
#define S_TOT    (T_TOKENS*2)   // 65536 routed slots
#define S_PAD    66048          // 65536 + 8*64 worst-case per-expert 64-padding

typedef __attribute__((ext_vector_type(8))) short bf16x8;
typedef __attribute__((ext_vector_type(4))) float f32x4;

__device__ __forceinline__ unsigned short f2bf(float f) {
    unsigned u = __float_as_uint(f);
    return (unsigned short)((u + 0x7FFFu + ((u >> 16) & 1u)) >> 16);  // RNE
}
__device__ __forceinline__ unsigned pack_bf2(float a, float b) {
    return (unsigned)f2bf(a) | ((unsigned)f2bf(b) << 16);
}

// async global->LDS, 16B per lane. LDS dest must be wave-uniform base + lane*16.
__device__ __forceinline__ void async16(void* lds, const void* g) {
    __builtin_amdgcn_global_load_lds(
        (const __attribute__((address_space(1))) unsigned int*)g,
        (__attribute__((address_space(3))) unsigned int*)lds, 16, 0, 0);
}

// ---------------- W fp32 [e][k][n] -> bf16 transposed [e][n][k] ----------------
__global__ void convw_kernel(const float* __restrict__ W, unsigned short* __restrict__ WT) {
    int idx = blockIdx.x * 256 + threadIdx.x;
    float v = W[idx];                                // coalesced read
    int n  = idx & 255;
    int ek = idx >> 8;                               // e*768 + k
    int k  = ek % D_IN;
    int e  = ek / D_IN;
    WT[(size_t)e * (D_IN * D_OUT) + (size_t)n * D_IN + k] = f2bf(v);
}

// ---- gate stage 1: k-split partial logits. grid=(512,4): 64 tokens x 192 k per block.
// 64x65 fp32 tile: conflict-free reads (bank (l+kk)%32); fuses xbf emit for its slice.
// gW reads wave-uniform -> scalar/constant-cache. 2048 waves = 8/CU.
__global__ __launch_bounds__(64) void gate_partial_kernel(
        const float* __restrict__ x, const float* __restrict__ gW,
        unsigned short* __restrict__ xbf, float* __restrict__ partial) {
    __shared__ float tile[64 * 65];
    int tid = threadIdx.x;
    int t0  = blockIdx.x * 64;
    int kq  = blockIdx.y;                            // k-quarter 0..3
    int c16 = tid & 15, rb = tid >> 4;
    float acc[8] = {0,0,0,0,0,0,0,0};
    #pragma unroll 1
    for (int j = 0; j < 3; j++) {
        int kc = kq * 192 + j * 64;
        #pragma unroll
        for (int i = 0; i < 16; i++) {
            int row = i * 4 + rb;
            size_t g = (size_t)(t0 + row) * D_IN + kc + c16 * 4;
            float4 v = *(const float4*)(x + g);
            uint2 p; p.x = pack_bf2(v.x, v.y); p.y = pack_bf2(v.z, v.w);
            *(uint2*)(xbf + g) = p;                  // fused bf16 emit (coalesced 8B)
            float* d = &tile[row * 65 + c16 * 4];
            d[0] = v.x; d[1] = v.y; d[2] = v.z; d[3] = v.w;  // ~2-way banks: free
        }
        __syncthreads();
        const float* gr = gW + (size_t)kc * 8;       // wave-uniform -> s_load
        #pragma unroll 8
        for (int kk = 0; kk < 64; kk++) {
            float xv = tile[tid * 65 + kk];          // bank (l+kk)%32: conflict-free
            #pragma unroll
            for (int e = 0; e < 8; e++) acc[e] += xv * gr[kk * 8 + e];
        }
        __syncthreads();
    }
    float* dst = partial + ((size_t)kq * T_TOKENS + t0 + tid) * 8;
    float4 o0 = {acc[0], acc[1], acc[2], acc[3]};
    float4 o1 = {acc[4], acc[5], acc[6], acc[7]};
    *(float4*)dst = o0; *(float4*)(dst + 4) = o1;    // 32B/token, coalesced
}

// ---- gate stage 2: sum partials (FIXED order: deterministic), softmax, top-2, hist ----
__global__ __launch_bounds__(256) void gate_final_kernel(
        const float* __restrict__ partial, const float* __restrict__ gb,
        float* __restrict__ topk_w, int* __restrict__ topk_e, int* __restrict__ counts) {
    __shared__ int h[8];
    int tid = threadIdx.x;
    if (tid < 8) h[tid] = 0;
    __syncthreads();
    int t = blockIdx.x * 256 + tid;
    float acc[8] = {0,0,0,0,0,0,0,0};
    #pragma unroll
    for (int q = 0; q < 4; q++) {                    // fixed summation order
        const float* p = partial + ((size_t)q * T_TOKENS + t) * 8;
        float4 a = *(const float4*)p;
        float4 b = *(const float4*)(p + 4);
        acc[0] += a.x; acc[1] += a.y; acc[2] += a.z; acc[3] += a.w;
        acc[4] += b.x; acc[5] += b.y; acc[6] += b.z; acc[7] += b.w;
    }
    float mx = -1e30f;
    #pragma unroll
    for (int e = 0; e < 8; e++) { acc[e] += gb[e]; mx = fmaxf(mx, acc[e]); }
    float w[8], s = 0.f;
    #pragma unroll
    for (int e = 0; e < 8; e++) { w[e] = expf(acc[e] - mx); s += w[e]; }
    float inv = 1.0f / s;
    int e0 = 0; float b0 = -1.f;
    #pragma unroll
    for (int e = 0; e < 8; e++) if (w[e] > b0) { b0 = w[e]; e0 = e; }   // ties -> lowest idx
    int e1 = 0; float b1 = -1.f;
    #pragma unroll
    for (int e = 0; e < 8; e++) if (e != e0 && w[e] > b1) { b1 = w[e]; e1 = e; }
    topk_w[t*2]   = b0 * inv;
    topk_w[t*2+1] = b1 * inv;
    topk_e[t*2]   = e0;
    topk_e[t*2+1] = e1;
    atomicAdd(&h[e0], 1); atomicAdd(&h[e1], 1);
    __syncthreads();
    if (tid < 8) atomicAdd(&counts[tid], h[tid]);
}

// ---- scatter (token,w) into expert buckets + inverse map; offsets computed locally ----
__global__ void scatter_kernel(const int* __restrict__ topk_e, const float* __restrict__ topk_w,
                               const int* __restrict__ counts, int* __restrict__ cursors,
                               int* __restrict__ slot_token, float* __restrict__ slot_w,
                               int* __restrict__ inv_slot) {
    int offs[9]; offs[0] = 0;
    #pragma unroll
    for (int e = 0; e < 8; e++) offs[e+1] = offs[e] + ((counts[e] + 63) & ~63);
    __shared__ int hcnt[8], hbase[8];
    if (threadIdx.x < 8) hcnt[threadIdx.x] = 0;
    __syncthreads();
    int idx[4], ee[4], lr[4];
    int base = blockIdx.x * 256 * 4 + threadIdx.x;
    #pragma unroll
    for (int j = 0; j < 4; j++) {
        idx[j] = base + j * 256;
        ee[j]  = topk_e[idx[j]];
        lr[j]  = atomicAdd(&hcnt[ee[j]], 1);
    }
    __syncthreads();
    if (threadIdx.x < 8) hbase[threadIdx.x] = atomicAdd(&cursors[threadIdx.x], hcnt[threadIdx.x]);
    __syncthreads();
    #pragma unroll
    for (int j = 0; j < 4; j++) {
        int slot = offs[ee[j]] + hbase[ee[j]] + lr[j];
        slot_token[slot] = idx[j] >> 1;
        slot_w[slot]     = topk_w[idx[j]];
        inv_slot[idx[j]] = slot;
    }
}

// ---- routed GEMM: 64 slots x 256 cols/block, BK=32, LDS double-buffered, bias fused ---
// ROUTED: plain stores of (acc+bias) into routed[slot][col]; else atomic fallback.
template<bool ROUTED>
__global__ __launch_bounds__(256, 4) void moe_gemm_kernel(
        const unsigned short* __restrict__ xbf, const unsigned short* __restrict__ WT,
        const float* __restrict__ eb, const int* __restrict__ counts,
        const int* __restrict__ slot_token, const float* __restrict__ slot_w,
        float* __restrict__ dst) {
    __shared__ unsigned short A_lds[2][64 * 32];     // 2 x 4 KB
    __shared__ unsigned short B_lds[2][256 * 32];    // 2 x 16 KB

    int offs[9]; offs[0] = 0;
    #pragma unroll
    for (int e = 0; e < 8; e++) offs[e+1] = offs[e] + ((counts[e] + 63) & ~63);
    int row0 = blockIdx.x * 64;
    if (row0 >= offs[8]) return;                     // uniform exit
    int expert = 0;
    #pragma unroll
    for (int e = 0; e < 8; e++) if (row0 >= offs[e]) expert = e;

    int tid  = threadIdx.x;
    int wave = tid >> 6, lane = tid & 63;
    int lrow = lane & 15, lquad = lane >> 4;

    // staging source addresses (LDS dest linear-by-thread; chunk-rotate the SOURCE)
    int srow = tid >> 2;                             // A phys row
    int pch  = tid & 3;                              // phys 16B chunk
    int lc_a = (pch - (srow >> 1)) & 3;              // logical chunk at this phys slot
    int tokA = slot_token[row0 + srow];              // pad slots are 0 (valid row)
    const unsigned short* abase = xbf + (size_t)tokA * D_IN + lc_a * 8;

    const unsigned short* bb = WT + (size_t)expert * (D_IN * D_OUT);
    const unsigned short* bsrc[4];
    #pragma unroll
    for (int i = 0; i < 4; i++) {
        int ci = i * 256 + tid;
        int br = ci >> 2, bp = ci & 3;
        int lc = (bp - (br >> 1)) & 3;
        bsrc[i] = bb + (size_t)br * D_IN + lc * 8;
    }

    // frag LDS offsets (shorts), constant across K
    int a_off[4], b_off[4];
    #pragma unroll
    for (int m = 0; m < 4; m++) {
        int r = m * 16 + lrow;
        a_off[m] = r * 32 + ((lquad + (r >> 1)) & 3) * 8;
    }
    #pragma unroll
    for (int s = 0; s < 4; s++) {
        int r = wave * 64 + s * 16 + lrow;
        b_off[s] = r * 32 + ((lquad + (r >> 1)) & 3) * 8;
    }

    f32x4 acc[4][4];
    #pragma unroll
    for (int m = 0; m < 4; m++)
        #pragma unroll
        for (int s = 0; s < 4; s++) acc[m][s] = (f32x4){0,0,0,0};

    auto stage = [&](int k0, int p) {
        async16(&A_lds[p][tid * 8], abase + k0);
        #pragma unroll
        for (int i = 0; i < 4; i++) async16(&B_lds[p][(i * 256 + tid) * 8], bsrc[i] + k0);
    };

    stage(0, 0);
    #pragma unroll 1
    for (int s = 0; s < D_IN / 32; s++) {
        __syncthreads();                             // drains vmcnt: buf (s&1) ready
        if (s < D_IN / 32 - 1) stage((s + 1) * 32, (s + 1) & 1);  // overlap with MFMA below
        int p = s & 1;
        bf16x8 a[4];
        #pragma unroll
        for (int m = 0; m < 4; m++) a[m] = *(const bf16x8*)&A_lds[p][a_off[m]];
        #pragma unroll
        for (int q = 0; q < 4; q++) {
            bf16x8 b = *(const bf16x8*)&B_lds[p][b_off[q]];
            #pragma unroll
            for (int m = 0; m < 4; m++)
                acc[m][q] = __builtin_amdgcn_mfma_f32_16x16x32_bf16(a[m], b, acc[m][q], 0, 0, 0);
        }
    }

    // epilogue: D mapping col=lane&15, row=quad*4+reg
    float bias_s[4];
    #pragma unroll
    for (int q = 0; q < 4; q++) bias_s[q] = eb[expert * D_OUT + wave * 64 + q * 16 + lrow];
    #pragma unroll
    for (int m = 0; m < 4; m++) {
        #pragma unroll
        for (int r = 0; r < 4; r++) {
            int slot = row0 + m * 16 + lquad * 4 + r;
            if constexpr (ROUTED) {
                float* drow = dst + (size_t)slot * D_OUT;
                #pragma unroll
                for (int q = 0; q < 4; q++)
                    drow[wave * 64 + q * 16 + lrow] = acc[m][q][r] + bias_s[q];
            } else {
                int tk = slot_token[slot];
                float wgt = slot_w[slot];            // pads have wgt=0
                #pragma unroll
                for (int q = 0; q < 4; q++)
                    atomicAdd(dst + (size_t)tk * D_OUT + wave * 64 + q * 16 + lrow,
                              wgt * (acc[m][q][r] + bias_s[q]));
            }
        }
    }
}

// ---------------- combine: out[t] = w0*routed[s0] + w1*routed[s1] ----------------
__global__ void combine_kernel(const float* __restrict__ routed, const int* __restrict__ inv_slot,
                               const float* __restrict__ topk_w, float* __restrict__ out) {
    int flat = blockIdx.x * 256 + threadIdx.x;       // float4 index
    int t = flat >> 6, c = (flat & 63) * 4;
    int   s0 = inv_slot[t*2], s1 = inv_slot[t*2+1];
    float w0 = topk_w[t*2],   w1 = topk_w[t*2+1];
    float4 r0 = *(const float4*)(routed + (size_t)s0 * D_OUT + c);
    float4 r1 = *(const float4*)(routed + (size_t)s1 * D_OUT + c);
    float4 o;
    o.x = w0*r0.x + w1*r1.x; o.y = w0*r0.y + w1*r1.y;
    o.z = w0*r0.z + w1*r1.z; o.w = w0*r0.w + w1*r1.w;
    *(float4*)(out + (size_t)t * D_OUT + c) = o;
}

extern "C" void kernel_launch(void* const* d_in, const int* in_sizes, int n_in,
                              void* d_out, int out_size, void* d_ws, size_t ws_size,
                              hipStream_t stream) {
    const float* x  = (const float*)d_in[0];
    const float* gW = (const float*)d_in[1];
    const float* gb = (const float*)d_in[2];
    const float* eW = (const float*)d_in[3];
    const float* eb = (const float*)d_in[4];
    float* out = (float*)d_out;
    char* ws = (char*)d_ws;

    // ws layout
    float* topk_w      = (float*)(ws + 0);                 // 256 KB
    int*   topk_e      = (int*)  (ws + 262144);            // 256 KB
    int*   counts      = (int*)  (ws + 524288);            // 32 B
    int*   cursors     = (int*)  (ws + 524320);            // 32 B
    int*   slot_token  = (int*)  (ws + 524416);            // 264192 B (S_PAD)
    float* slot_w      = (float*)(ws + 788608);            // 264192 B (S_PAD)
    int*   inv_slot    = (int*)  (ws + 1052800);           // 262144 B (S_TOT)
    float* partial     = (float*)(ws + 1314944);           // 4 MB  [4][T][8] fp32
    unsigned short* WT = (unsigned short*)(ws + 5509248);  // 3 MB bf16 W^T
    unsigned short* xbf= (unsigned short*)(ws + 8654976);  // 48 MB bf16 x
    float* routed      = (float*)(ws + 58986624);          // 67.6 MB routed outputs
    const size_t NEED_ROUTED = 58986624 + (size_t)S_PAD * D_OUT * 4;  // ~121 MB
    bool use_routed = (ws_size >= NEED_ROUTED);

    hipMemsetAsync(ws + 524288, 0, 128, stream);            // counts + cursors
    hipMemsetAsync(slot_token, 0, 528384, stream);          // slot_token + slot_w -> 0

    convw_kernel       <<<N_EXP * D_IN * D_OUT / 256, 256, 0, stream>>>(eW, WT);
    gate_partial_kernel<<<dim3(T_TOKENS / 64, 4), 64, 0, stream>>>(x, gW, xbf, partial);
    gate_final_kernel  <<<T_TOKENS / 256, 256, 0, stream>>>(partial, gb, topk_w, topk_e, counts);
    scatter_kernel     <<<S_TOT / (256 * 4), 256, 0, stream>>>(topk_e, topk_w, counts, cursors,
                                                               slot_token, slot_w, inv_slot);
    if (use_routed) {
        moe_gemm_kernel<true><<<S_PAD / 64, 256, 0, stream>>>(xbf, WT, eb, counts,
                                                              slot_token, slot_w, routed);
        combine_kernel<<<T_TOKENS * D_OUT / 4 / 256, 256, 0, stream>>>(routed, inv_slot,
                                                                       topk_w, out);
    } else {
        hipMemsetAsync(out, 0, (size_t)out_size * sizeof(float), stream);
        moe_gemm_kernel<false><<<S_PAD / 64, 256, 0, stream>>>(xbf, WT, eb, counts,
                                                               slot_token, slot_w, out);
    }
}

// Round 5
// 271.747 us; speedup vs baseline: 1.3968x; 1.0091x over previous
//
#include <hip/hip_runtime.h>
#include <hip/hip_bf16.h>
#include <stdint.h>

// Problem constants (fixed by reference setup_inputs)
#define T_TOKENS 32768     // 32*1024
#define D_IN     768
#define D_OUT    256
#define N_EXP    8
#define S_TOT    (T_TOKENS*2)   // 65536 routed slots
#define S_PAD    66560          // 65536 + 8*128 worst-case per-expert 128-padding
#define KSPLIT   6              // gate k-split: 768 = 6 x 128

typedef __attribute__((ext_vector_type(8))) short bf16x8;
typedef __attribute__((ext_vector_type(4))) float f32x4;

__device__ __forceinline__ unsigned short f2bf(float f) {
    unsigned u = __float_as_uint(f);
    return (unsigned short)((u + 0x7FFFu + ((u >> 16) & 1u)) >> 16);  // RNE
}
__device__ __forceinline__ unsigned pack_bf2(float a, float b) {
    return (unsigned)f2bf(a) | ((unsigned)f2bf(b) << 16);
}

// async global->LDS, 16B per lane. LDS dest must be wave-uniform base + lane*16.
__device__ __forceinline__ void async16(void* lds, const void* g) {
    __builtin_amdgcn_global_load_lds(
        (const __attribute__((address_space(1))) unsigned int*)g,
        (__attribute__((address_space(3))) unsigned int*)lds, 16, 0, 0);
}

// ---- W fp32 [e][k][n] -> bf16 transposed [e][n][k]; also zeroes counts+cursors ----
__global__ void convw_kernel(const float* __restrict__ W, unsigned short* __restrict__ WT,
                             int* __restrict__ zero16) {
    if (blockIdx.x == 0 && threadIdx.x < 16) zero16[threadIdx.x] = 0;  // counts+cursors
    int idx = blockIdx.x * 256 + threadIdx.x;
    float v = W[idx];                                // coalesced read
    int n  = idx & 255;
    int ek = idx >> 8;                               // e*768 + k
    int k  = ek % D_IN;
    int e  = ek / D_IN;
    WT[(size_t)e * (D_IN * D_OUT) + (size_t)n * D_IN + k] = f2bf(v);
}

// ---- gate stage 1: k-split partial logits. grid=(512,KSPLIT): 64 tokens x 128 k each.
// 64x65 fp32 tile: conflict-free LDS; fuses xbf emit for its slice.
// gW reads wave-uniform -> scalar/constant-cache.
__global__ __launch_bounds__(64) void gate_partial_kernel(
        const float* __restrict__ x, const float* __restrict__ gW,
        unsigned short* __restrict__ xbf, float* __restrict__ partial) {
    __shared__ float tile[64 * 65];
    int tid = threadIdx.x;
    int t0  = blockIdx.x * 64;
    int kq  = blockIdx.y;                            // k-slice 0..KSPLIT-1
    int c16 = tid & 15, rb = tid >> 4;
    float acc[8] = {0,0,0,0,0,0,0,0};
    #pragma unroll 1
    for (int j = 0; j < 2; j++) {
        int kc = kq * 128 + j * 64;
        #pragma unroll
        for (int i = 0; i < 16; i++) {
            int row = i * 4 + rb;
            size_t g = (size_t)(t0 + row) * D_IN + kc + c16 * 4;
            float4 v = *(const float4*)(x + g);
            uint2 p; p.x = pack_bf2(v.x, v.y); p.y = pack_bf2(v.z, v.w);
            *(uint2*)(xbf + g) = p;                  // fused bf16 emit (coalesced 8B)
            float* d = &tile[row * 65 + c16 * 4];
            d[0] = v.x; d[1] = v.y; d[2] = v.z; d[3] = v.w;  // ~2-way banks: free
        }
        __syncthreads();
        const float* gr = gW + (size_t)kc * 8;       // wave-uniform -> s_load
        #pragma unroll 8
        for (int kk = 0; kk < 64; kk++) {
            float xv = tile[tid * 65 + kk];          // bank (l+kk)%32: conflict-free
            #pragma unroll
            for (int e = 0; e < 8; e++) acc[e] += xv * gr[kk * 8 + e];
        }
        __syncthreads();
    }
    float* dst = partial + ((size_t)kq * T_TOKENS + t0 + tid) * 8;
    float4 o0 = {acc[0], acc[1], acc[2], acc[3]};
    float4 o1 = {acc[4], acc[5], acc[6], acc[7]};
    *(float4*)dst = o0; *(float4*)(dst + 4) = o1;    // 32B/token, coalesced
}

// ---- gate stage 2: sum partials (FIXED order: deterministic), softmax, top-2, hist ----
__global__ __launch_bounds__(256) void gate_final_kernel(
        const float* __restrict__ partial, const float* __restrict__ gb,
        float* __restrict__ topk_w, int* __restrict__ topk_e, int* __restrict__ counts) {
    __shared__ int h[8];
    int tid = threadIdx.x;
    if (tid < 8) h[tid] = 0;
    __syncthreads();
    int t = blockIdx.x * 256 + tid;
    float acc[8] = {0,0,0,0,0,0,0,0};
    #pragma unroll
    for (int q = 0; q < KSPLIT; q++) {               // fixed summation order
        const float* p = partial + ((size_t)q * T_TOKENS + t) * 8;
        float4 a = *(const float4*)p;
        float4 b = *(const float4*)(p + 4);
        acc[0] += a.x; acc[1] += a.y; acc[2] += a.z; acc[3] += a.w;
        acc[4] += b.x; acc[5] += b.y; acc[6] += b.z; acc[7] += b.w;
    }
    float mx = -1e30f;
    #pragma unroll
    for (int e = 0; e < 8; e++) { acc[e] += gb[e]; mx = fmaxf(mx, acc[e]); }
    float w[8], s = 0.f;
    #pragma unroll
    for (int e = 0; e < 8; e++) { w[e] = expf(acc[e] - mx); s += w[e]; }
    float inv = 1.0f / s;
    int e0 = 0; float b0 = -1.f;
    #pragma unroll
    for (int e = 0; e < 8; e++) if (w[e] > b0) { b0 = w[e]; e0 = e; }   // ties -> lowest idx
    int e1 = 0; float b1 = -1.f;
    #pragma unroll
    for (int e = 0; e < 8; e++) if (e != e0 && w[e] > b1) { b1 = w[e]; e1 = e; }
    topk_w[t*2]   = b0 * inv;
    topk_w[t*2+1] = b1 * inv;
    topk_e[t*2]   = e0;
    topk_e[t*2+1] = e1;
    atomicAdd(&h[e0], 1); atomicAdd(&h[e1], 1);
    __syncthreads();
    if (tid < 8) atomicAdd(&counts[tid], h[tid]);
}

// ---- scatter (token,w) into expert buckets + inverse map; 128-aligned regions ----
__global__ void scatter_kernel(const int* __restrict__ topk_e, const float* __restrict__ topk_w,
                               const int* __restrict__ counts, int* __restrict__ cursors,
                               int* __restrict__ slot_token, float* __restrict__ slot_w,
                               int* __restrict__ inv_slot) {
    int offs[9]; offs[0] = 0;
    #pragma unroll
    for (int e = 0; e < 8; e++) offs[e+1] = offs[e] + ((counts[e] + 127) & ~127);
    __shared__ int hcnt[8], hbase[8];
    if (threadIdx.x < 8) hcnt[threadIdx.x] = 0;
    __syncthreads();
    int idx[4], ee[4], lr[4];
    int base = blockIdx.x * 256 * 4 + threadIdx.x;
    #pragma unroll
    for (int j = 0; j < 4; j++) {
        idx[j] = base + j * 256;
        ee[j]  = topk_e[idx[j]];
        lr[j]  = atomicAdd(&hcnt[ee[j]], 1);
    }
    __syncthreads();
    if (threadIdx.x < 8) hbase[threadIdx.x] = atomicAdd(&cursors[threadIdx.x], hcnt[threadIdx.x]);
    __syncthreads();
    #pragma unroll
    for (int j = 0; j < 4; j++) {
        int slot = offs[ee[j]] + hbase[ee[j]] + lr[j];
        slot_token[slot] = idx[j] >> 1;
        slot_w[slot]     = topk_w[idx[j]];
        inv_slot[idx[j]] = slot;
    }
}

// ---- routed GEMM: 128 slots x 256 cols/block, BK=32, LDS double-buffered, bias fused ---
// 32 MFMA/wave/K-step (2x barrier amortization vs 64-row tile). 48 KB LDS -> 2 blocks/CU.
// Pad slots: token clamped (garbage rows computed but never read by combine).
template<bool ROUTED>
__global__ __launch_bounds__(256, 2) void moe_gemm_kernel(
        const unsigned short* __restrict__ xbf, const unsigned short* __restrict__ WT,
        const float* __restrict__ eb, const int* __restrict__ counts,
        const int* __restrict__ slot_token, const float* __restrict__ slot_w,
        float* __restrict__ dst) {
    __shared__ unsigned short A_lds[2][128 * 32];    // 2 x 8 KB
    __shared__ unsigned short B_lds[2][256 * 32];    // 2 x 16 KB

    int offs[9]; offs[0] = 0;
    #pragma unroll
    for (int e = 0; e < 8; e++) offs[e+1] = offs[e] + ((counts[e] + 127) & ~127);
    int row0 = blockIdx.x * 128;
    if (row0 >= offs[8]) return;                     // uniform exit
    int expert = 0;
    #pragma unroll
    for (int e = 0; e < 8; e++) if (row0 >= offs[e]) expert = e;

    int tid  = threadIdx.x;
    int wave = tid >> 6, lane = tid & 63;
    int lrow = lane & 15, lquad = lane >> 4;

    // ---- staging sources (LDS dest linear-by-thread; chunk-rotate the SOURCE) ----
    // A: 512 16B-chunks (128 rows x 4); call i covers chunk c = i*256+tid
    const unsigned short* asrc[2];
    #pragma unroll
    for (int i = 0; i < 2; i++) {
        int c = i * 256 + tid;
        int r = c >> 2, p = c & 3;
        int lc = (p - (r >> 1)) & 3;                 // logical chunk at this phys slot
        int tok = slot_token[row0 + r];
        tok = tok < 0 ? 0 : (tok >= T_TOKENS ? 0 : tok);   // pads hold garbage: clamp
        asrc[i] = xbf + (size_t)tok * D_IN + lc * 8;
    }
    // B: 1024 chunks (256 rows x 4); call i covers chunk c = i*256+tid
    const unsigned short* bb = WT + (size_t)expert * (D_IN * D_OUT);
    const unsigned short* bsrc[4];
    #pragma unroll
    for (int i = 0; i < 4; i++) {
        int c = i * 256 + tid;
        int r = c >> 2, p = c & 3;
        int lc = (p - (r >> 1)) & 3;
        bsrc[i] = bb + (size_t)r * D_IN + lc * 8;
    }

    // frag LDS offsets (shorts), constant across K
    int a_off[8], b_off[4];
    #pragma unroll
    for (int m = 0; m < 8; m++) {
        int r = m * 16 + lrow;
        a_off[m] = r * 32 + ((lquad + (r >> 1)) & 3) * 8;
    }
    #pragma unroll
    for (int q = 0; q < 4; q++) {
        int r = wave * 64 + q * 16 + lrow;
        b_off[q] = r * 32 + ((lquad + (r >> 1)) & 3) * 8;
    }

    f32x4 acc[8][4];
    #pragma unroll
    for (int m = 0; m < 8; m++)
        #pragma unroll
        for (int q = 0; q < 4; q++) acc[m][q] = (f32x4){0,0,0,0};

    auto stage = [&](int k0, int p) {
        #pragma unroll
        for (int i = 0; i < 2; i++) async16(&A_lds[p][(i * 256 + tid) * 8], asrc[i] + k0);
        #pragma unroll
        for (int i = 0; i < 4; i++) async16(&B_lds[p][(i * 256 + tid) * 8], bsrc[i] + k0);
    };

    stage(0, 0);
    #pragma unroll 1
    for (int s = 0; s < D_IN / 32; s++) {
        __syncthreads();                             // drains vmcnt: buf (s&1) ready
        if (s < D_IN / 32 - 1) stage((s + 1) * 32, (s + 1) & 1);  // overlap with MFMA
        int p = s & 1;
        bf16x8 a[8];
        #pragma unroll
        for (int m = 0; m < 8; m++) a[m] = *(const bf16x8*)&A_lds[p][a_off[m]];
        #pragma unroll
        for (int q = 0; q < 4; q++) {
            bf16x8 b = *(const bf16x8*)&B_lds[p][b_off[q]];
            #pragma unroll
            for (int m = 0; m < 8; m++)
                acc[m][q] = __builtin_amdgcn_mfma_f32_16x16x32_bf16(a[m], b, acc[m][q], 0, 0, 0);
        }
    }

    // epilogue: D mapping col=lane&15, row=quad*4+reg
    float bias_q[4];
    #pragma unroll
    for (int q = 0; q < 4; q++) bias_q[q] = eb[expert * D_OUT + wave * 64 + q * 16 + lrow];
    #pragma unroll
    for (int m = 0; m < 8; m++) {
        #pragma unroll
        for (int r = 0; r < 4; r++) {
            int slot = row0 + m * 16 + lquad * 4 + r;
            if constexpr (ROUTED) {
                float* drow = dst + (size_t)slot * D_OUT + wave * 64;
                #pragma unroll
                for (int q = 0; q < 4; q++)
                    drow[q * 16 + lrow] = acc[m][q][r] + bias_q[q];
            } else {
                int tk = slot_token[slot];
                float wgt = slot_w[slot];            // pads have wgt=0 (memset in this path)
                #pragma unroll
                for (int q = 0; q < 4; q++)
                    atomicAdd(dst + (size_t)tk * D_OUT + wave * 64 + q * 16 + lrow,
                              wgt * (acc[m][q][r] + bias_q[q]));
            }
        }
    }
}

// ---------------- combine: out[t] = w0*routed[s0] + w1*routed[s1] ----------------
__global__ void combine_kernel(const float* __restrict__ routed, const int* __restrict__ inv_slot,
                               const float* __restrict__ topk_w, float* __restrict__ out) {
    int flat = blockIdx.x * 256 + threadIdx.x;       // float4 index
    int t = flat >> 6, c = (flat & 63) * 4;
    int   s0 = inv_slot[t*2], s1 = inv_slot[t*2+1];
    float w0 = topk_w[t*2],   w1 = topk_w[t*2+1];
    float4 r0 = *(const float4*)(routed + (size_t)s0 * D_OUT + c);
    float4 r1 = *(const float4*)(routed + (size_t)s1 * D_OUT + c);
    float4 o;
    o.x = w0*r0.x + w1*r1.x; o.y = w0*r0.y + w1*r1.y;
    o.z = w0*r0.z + w1*r1.z; o.w = w0*r0.w + w1*r1.w;
    *(float4*)(out + (size_t)t * D_OUT + c) = o;
}

extern "C" void kernel_launch(void* const* d_in, const int* in_sizes, int n_in,
                              void* d_out, int out_size, void* d_ws, size_t ws_size,
                              hipStream_t stream) {
    const float* x  = (const float*)d_in[0];
    const float* gW = (const float*)d_in[1];
    const float* gb = (const float*)d_in[2];
    const float* eW = (const float*)d_in[3];
    const float* eb = (const float*)d_in[4];
    float* out = (float*)d_out;
    char* ws = (char*)d_ws;

    // ws layout
    float* topk_w      = (float*)(ws + 0);                 // 256 KB
    int*   topk_e      = (int*)  (ws + 262144);            // 256 KB
    int*   counts      = (int*)  (ws + 524288);            // 8 ints
    int*   cursors     = (int*)  (ws + 524320);            // 8 ints  (contiguous w/ counts)
    int*   slot_token  = (int*)  (ws + 524416);            // 266240 B (S_PAD)
    float* slot_w      = (float*)(ws + 790656);            // 266240 B (S_PAD)
    int*   inv_slot    = (int*)  (ws + 1056896);           // 262144 B (S_TOT)
    float* partial     = (float*)(ws + 1319040);           // 6 MB  [KSPLIT][T][8] fp32
    unsigned short* WT = (unsigned short*)(ws + 7610496);  // 3 MB bf16 W^T
    unsigned short* xbf= (unsigned short*)(ws + 10756224); // 48 MB bf16 x
    float* routed      = (float*)(ws + 61087872);          // 68 MB routed outputs
    const size_t NEED_ROUTED = 61087872 + (size_t)S_PAD * D_OUT * 4;  // ~129 MB
    bool use_routed = (ws_size >= NEED_ROUTED);

    convw_kernel       <<<N_EXP * D_IN * D_OUT / 256, 256, 0, stream>>>(eW, WT, counts);
    gate_partial_kernel<<<dim3(T_TOKENS / 64, KSPLIT), 64, 0, stream>>>(x, gW, xbf, partial);
    gate_final_kernel  <<<T_TOKENS / 256, 256, 0, stream>>>(partial, gb, topk_w, topk_e, counts);
    scatter_kernel     <<<S_TOT / (256 * 4), 256, 0, stream>>>(topk_e, topk_w, counts, cursors,
                                                               slot_token, slot_w, inv_slot);
    if (use_routed) {
        moe_gemm_kernel<true><<<S_PAD / 128, 256, 0, stream>>>(xbf, WT, eb, counts,
                                                               slot_token, slot_w, routed);
        combine_kernel<<<T_TOKENS * D_OUT / 4 / 256, 256, 0, stream>>>(routed, inv_slot,
                                                                       topk_w, out);
    } else {
        // fallback: pads must be (token=0, w=0) for the atomic path
        hipMemsetAsync(slot_token, 0, 532480, stream);
        hipMemsetAsync(out, 0, (size_t)out_size * sizeof(float), stream);
        moe_gemm_kernel<false><<<S_PAD / 128, 256, 0, stream>>>(xbf, WT, eb, counts,
                                                                slot_token, slot_w, out);
    }
}

// Round 6
// 269.857 us; speedup vs baseline: 1.4066x; 1.0070x over previous
//
#include <hip/hip_runtime.h>
#include <hip/hip_bf16.h>
#include <stdint.h>

// Problem constants (fixed by reference setup_inputs)
#define T_TOKENS 32768     // 32*1024
#define D_IN     768
#define D_OUT    256
#define N_EXP    8
#define S_TOT    (T_TOKENS*2)   // 65536 routed slots
#define S_PAD    66560          // 65536 + 8*128 worst-case per-expert 128-padding
#define KSPLIT   6              // gate k-split: 768 = 6 x 128
#define NKB      24             // K-blocks of 32 in d_in

typedef __attribute__((ext_vector_type(8))) short bf16x8;
typedef __attribute__((ext_vector_type(4))) float f32x4;

__device__ __forceinline__ unsigned short f2bf(float f) {
    unsigned u = __float_as_uint(f);
    return (unsigned short)((u + 0x7FFFu + ((u >> 16) & 1u)) >> 16);  // RNE
}
__device__ __forceinline__ unsigned pack_bf2(float a, float b) {
    return (unsigned)f2bf(a) | ((unsigned)f2bf(b) << 16);
}

// async global->LDS, 16B per lane. LDS dest must be wave-uniform base + lane*16.
__device__ __forceinline__ void async16(void* lds, const void* g) {
    __builtin_amdgcn_global_load_lds(
        (const __attribute__((address_space(1))) unsigned int*)g,
        (__attribute__((address_space(3))) unsigned int*)lds, 16, 0, 0);
}

// ---- W fp32 [e][k][n] -> bf16 k-blocked [e][kb][n][32kk]; zeroes counts+cursors ----
// Each (e,kb) tile is a contiguous 16 KB slab -> GEMM B staging is fully coalesced.
__global__ __launch_bounds__(256) void convw_kernel(
        const float* __restrict__ W, unsigned short* __restrict__ WTb,
        int* __restrict__ zero16) {
    if (blockIdx.x == 0 && threadIdx.x < 16) zero16[threadIdx.x] = 0;  // counts+cursors
    int eb_ = blockIdx.x;                            // e*NKB + kb, 0..191
    int n = threadIdx.x;
    const float* src = W + ((size_t)(eb_ / NKB) * D_IN + (eb_ % NKB) * 32) * 256 + n;
    unsigned pk[16];
    #pragma unroll
    for (int j = 0; j < 16; j++)                     // reads coalesced (n fastest)
        pk[j] = pack_bf2(src[(2*j) * 256], src[(2*j+1) * 256]);
    unsigned* dst = (unsigned*)(WTb + ((size_t)eb_ * 256 + n) * 32);  // 64 B/thread contig
    #pragma unroll
    for (int j = 0; j < 16; j++) dst[j] = pk[j];
}

// ---- gate stage 1: k-split partial logits. grid=(512,KSPLIT): 64 tokens x 128 k each.
__global__ __launch_bounds__(64) void gate_partial_kernel(
        const float* __restrict__ x, const float* __restrict__ gW,
        unsigned short* __restrict__ xbf, float* __restrict__ partial) {
    __shared__ float tile[64 * 65];
    int tid = threadIdx.x;
    int t0  = blockIdx.x * 64;
    int kq  = blockIdx.y;                            // k-slice 0..KSPLIT-1
    int c16 = tid & 15, rb = tid >> 4;
    float acc[8] = {0,0,0,0,0,0,0,0};
    #pragma unroll 1
    for (int j = 0; j < 2; j++) {
        int kc = kq * 128 + j * 64;
        #pragma unroll
        for (int i = 0; i < 16; i++) {
            int row = i * 4 + rb;
            size_t g = (size_t)(t0 + row) * D_IN + kc + c16 * 4;
            float4 v = *(const float4*)(x + g);
            uint2 p; p.x = pack_bf2(v.x, v.y); p.y = pack_bf2(v.z, v.w);
            *(uint2*)(xbf + g) = p;                  // fused bf16 emit (coalesced 8B)
            float* d = &tile[row * 65 + c16 * 4];
            d[0] = v.x; d[1] = v.y; d[2] = v.z; d[3] = v.w;  // ~2-way banks: free
        }
        __syncthreads();
        const float* gr = gW + (size_t)kc * 8;       // wave-uniform -> s_load
        #pragma unroll 8
        for (int kk = 0; kk < 64; kk++) {
            float xv = tile[tid * 65 + kk];          // bank (l+kk)%32: conflict-free
            #pragma unroll
            for (int e = 0; e < 8; e++) acc[e] += xv * gr[kk * 8 + e];
        }
        __syncthreads();
    }
    float* dst = partial + ((size_t)kq * T_TOKENS + t0 + tid) * 8;
    float4 o0 = {acc[0], acc[1], acc[2], acc[3]};
    float4 o1 = {acc[4], acc[5], acc[6], acc[7]};
    *(float4*)dst = o0; *(float4*)(dst + 4) = o1;    // 32B/token, coalesced
}

// ---- gate stage 2: sum partials (FIXED order: deterministic), softmax, top-2, hist ----
__global__ __launch_bounds__(256) void gate_final_kernel(
        const float* __restrict__ partial, const float* __restrict__ gb,
        float* __restrict__ topk_w, int* __restrict__ topk_e, int* __restrict__ counts) {
    __shared__ int h[8];
    int tid = threadIdx.x;
    if (tid < 8) h[tid] = 0;
    __syncthreads();
    int t = blockIdx.x * 256 + tid;
    float acc[8] = {0,0,0,0,0,0,0,0};
    #pragma unroll
    for (int q = 0; q < KSPLIT; q++) {               // fixed summation order
        const float* p = partial + ((size_t)q * T_TOKENS + t) * 8;
        float4 a = *(const float4*)p;
        float4 b = *(const float4*)(p + 4);
        acc[0] += a.x; acc[1] += a.y; acc[2] += a.z; acc[3] += a.w;
        acc[4] += b.x; acc[5] += b.y; acc[6] += b.z; acc[7] += b.w;
    }
    float mx = -1e30f;
    #pragma unroll
    for (int e = 0; e < 8; e++) { acc[e] += gb[e]; mx = fmaxf(mx, acc[e]); }
    float w[8], s = 0.f;
    #pragma unroll
    for (int e = 0; e < 8; e++) { w[e] = expf(acc[e] - mx); s += w[e]; }
    float inv = 1.0f / s;
    int e0 = 0; float b0 = -1.f;
    #pragma unroll
    for (int e = 0; e < 8; e++) if (w[e] > b0) { b0 = w[e]; e0 = e; }   // ties -> lowest idx
    int e1 = 0; float b1 = -1.f;
    #pragma unroll
    for (int e = 0; e < 8; e++) if (e != e0 && w[e] > b1) { b1 = w[e]; e1 = e; }
    topk_w[t*2]   = b0 * inv;
    topk_w[t*2+1] = b1 * inv;
    topk_e[t*2]   = e0;
    topk_e[t*2+1] = e1;
    atomicAdd(&h[e0], 1); atomicAdd(&h[e1], 1);
    __syncthreads();
    if (tid < 8) atomicAdd(&counts[tid], h[tid]);
}

// ---- scatter (token,w) into expert buckets + inverse map; 128-aligned regions ----
__global__ void scatter_kernel(const int* __restrict__ topk_e, const float* __restrict__ topk_w,
                               const int* __restrict__ counts, int* __restrict__ cursors,
                               int* __restrict__ slot_token, float* __restrict__ slot_w,
                               int* __restrict__ inv_slot) {
    int offs[9]; offs[0] = 0;
    #pragma unroll
    for (int e = 0; e < 8; e++) offs[e+1] = offs[e] + ((counts[e] + 127) & ~127);
    __shared__ int hcnt[8], hbase[8];
    if (threadIdx.x < 8) hcnt[threadIdx.x] = 0;
    __syncthreads();
    int idx[4], ee[4], lr[4];
    int base = blockIdx.x * 256 * 4 + threadIdx.x;
    #pragma unroll
    for (int j = 0; j < 4; j++) {
        idx[j] = base + j * 256;
        ee[j]  = topk_e[idx[j]];
        lr[j]  = atomicAdd(&hcnt[ee[j]], 1);
    }
    __syncthreads();
    if (threadIdx.x < 8) hbase[threadIdx.x] = atomicAdd(&cursors[threadIdx.x], hcnt[threadIdx.x]);
    __syncthreads();
    #pragma unroll
    for (int j = 0; j < 4; j++) {
        int slot = offs[ee[j]] + hbase[ee[j]] + lr[j];
        slot_token[slot] = idx[j] >> 1;
        slot_w[slot]     = topk_w[idx[j]];
        inv_slot[idx[j]] = slot;
    }
}

// ---- routed GEMM: 128 slots x 256 cols/block, BK=32, 3-stage pipeline, raw barriers ----
// Prefetch distance 2 via manual `s_waitcnt vmcnt(6)` + raw `s_barrier` (the m97-style
// __syncthreads drain caps distance at 1 and stalled ~84% of cycles at R4/R5).
template<bool ROUTED>
__global__ __launch_bounds__(256, 2) void moe_gemm_kernel(
        const unsigned short* __restrict__ xbf, const unsigned short* __restrict__ WTb,
        const float* __restrict__ eb, const int* __restrict__ counts,
        const int* __restrict__ slot_token, const float* __restrict__ slot_w,
        float* __restrict__ dst) {
    __shared__ unsigned short A_lds[3][128 * 32];    // 3 x 8 KB
    __shared__ unsigned short B_lds[3][256 * 32];    // 3 x 16 KB  -> 72 KB total

    int offs[9]; offs[0] = 0;
    #pragma unroll
    for (int e = 0; e < 8; e++) offs[e+1] = offs[e] + ((counts[e] + 127) & ~127);
    int row0 = blockIdx.x * 128;
    if (row0 >= offs[8]) return;                     // uniform exit
    int expert = 0;
    #pragma unroll
    for (int e = 0; e < 8; e++) if (row0 >= offs[e]) expert = e;

    int tid  = threadIdx.x;
    int wave = tid >> 6, lane = tid & 63;
    int lrow = lane & 15, lquad = lane >> 4;

    // ---- staging sources (LDS dest linear-by-thread; chunk-rotate the SOURCE) ----
    // A: 512 16B-chunks (128 rows x 4); gathered rows (row-major xbf)
    const unsigned short* asrc[2];
    #pragma unroll
    for (int i = 0; i < 2; i++) {
        int c = i * 256 + tid;
        int r = c >> 2, p = c & 3;
        int lc = (p - (r >> 1)) & 3;                 // logical chunk at this phys slot
        int tok = slot_token[row0 + r];
        tok = (tok < 0 || tok >= T_TOKENS) ? 0 : tok;  // pad slots hold poison: clamp
        asrc[i] = xbf + (size_t)tok * D_IN + lc * 8;
    }
    // B: k-blocked tile = contiguous 16 KB; per-thread offset within tile fixed
    const unsigned short* bexp = WTb + (size_t)expert * NKB * 8192;
    int boff[4];
    #pragma unroll
    for (int i = 0; i < 4; i++) {
        int c = i * 256 + tid;
        int r = c >> 2, p = c & 3;
        int lc = (p - (r >> 1)) & 3;
        boff[i] = r * 32 + lc * 8;                   // shorts within 16 KB tile
    }

    // frag LDS offsets (shorts), constant across K
    int a_off[8], b_off[4];
    #pragma unroll
    for (int m = 0; m < 8; m++) {
        int r = m * 16 + lrow;
        a_off[m] = r * 32 + ((lquad + (r >> 1)) & 3) * 8;
    }
    #pragma unroll
    for (int q = 0; q < 4; q++) {
        int r = wave * 64 + q * 16 + lrow;
        b_off[q] = r * 32 + ((lquad + (r >> 1)) & 3) * 8;
    }

    f32x4 acc[8][4];
    #pragma unroll
    for (int m = 0; m < 8; m++)
        #pragma unroll
        for (int q = 0; q < 4; q++) acc[m][q] = (f32x4){0,0,0,0};

    auto stage = [&](int kb, int st) {               // 6 VMEM instrs per wave
        #pragma unroll
        for (int i = 0; i < 2; i++)
            async16(&A_lds[st][(i * 256 + tid) * 8], asrc[i] + kb * 32);
        const unsigned short* tb = bexp + (size_t)kb * 8192;
        #pragma unroll
        for (int i = 0; i < 4; i++)
            async16(&B_lds[st][(i * 256 + tid) * 8], tb + boff[i]);
    };

    stage(0, 0);
    stage(1, 1);
    for (int s = 0; s < NKB; s++) {
        // wait: oldest in-flight stage (s) done; stage(s+1) may stay in flight
        if (s == NKB - 1) asm volatile("s_waitcnt vmcnt(0)" ::: "memory");
        else              asm volatile("s_waitcnt vmcnt(6)" ::: "memory");
        asm volatile("s_barrier" ::: "memory");      // raw: no compiler vmcnt(0) drain
        if (s + 2 < NKB) stage(s + 2, (s + 2) % 3);
        int p = s % 3;
        bf16x8 a[8];
        #pragma unroll
        for (int m = 0; m < 8; m++) a[m] = *(const bf16x8*)&A_lds[p][a_off[m]];
        #pragma unroll
        for (int q = 0; q < 4; q++) {
            bf16x8 b = *(const bf16x8*)&B_lds[p][b_off[q]];
            #pragma unroll
            for (int m = 0; m < 8; m++)
                acc[m][q] = __builtin_amdgcn_mfma_f32_16x16x32_bf16(a[m], b, acc[m][q], 0, 0, 0);
        }
    }

    // epilogue: D mapping col=lane&15, row=quad*4+reg
    float bias_q[4];
    #pragma unroll
    for (int q = 0; q < 4; q++) bias_q[q] = eb[expert * D_OUT + wave * 64 + q * 16 + lrow];
    #pragma unroll
    for (int m = 0; m < 8; m++) {
        #pragma unroll
        for (int r = 0; r < 4; r++) {
            int slot = row0 + m * 16 + lquad * 4 + r;
            if constexpr (ROUTED) {
                float* drow = dst + (size_t)slot * D_OUT + wave * 64;
                #pragma unroll
                for (int q = 0; q < 4; q++)
                    drow[q * 16 + lrow] = acc[m][q][r] + bias_q[q];
            } else {
                int tk = slot_token[slot];
                float wgt = slot_w[slot];            // pads have wgt=0 (memset in this path)
                #pragma unroll
                for (int q = 0; q < 4; q++)
                    atomicAdd(dst + (size_t)tk * D_OUT + wave * 64 + q * 16 + lrow,
                              wgt * (acc[m][q][r] + bias_q[q]));
            }
        }
    }
}

// ---------------- combine: out[t] = w0*routed[s0] + w1*routed[s1] ----------------
__global__ void combine_kernel(const float* __restrict__ routed, const int* __restrict__ inv_slot,
                               const float* __restrict__ topk_w, float* __restrict__ out) {
    int flat = blockIdx.x * 256 + threadIdx.x;       // float4 index
    int t = flat >> 6, c = (flat & 63) * 4;
    int   s0 = inv_slot[t*2], s1 = inv_slot[t*2+1];
    float w0 = topk_w[t*2],   w1 = topk_w[t*2+1];
    float4 r0 = *(const float4*)(routed + (size_t)s0 * D_OUT + c);
    float4 r1 = *(const float4*)(routed + (size_t)s1 * D_OUT + c);
    float4 o;
    o.x = w0*r0.x + w1*r1.x; o.y = w0*r0.y + w1*r1.y;
    o.z = w0*r0.z + w1*r1.z; o.w = w0*r0.w + w1*r1.w;
    *(float4*)(out + (size_t)t * D_OUT + c) = o;
}

extern "C" void kernel_launch(void* const* d_in, const int* in_sizes, int n_in,
                              void* d_out, int out_size, void* d_ws, size_t ws_size,
                              hipStream_t stream) {
    const float* x  = (const float*)d_in[0];
    const float* gW = (const float*)d_in[1];
    const float* gb = (const float*)d_in[2];
    const float* eW = (const float*)d_in[3];
    const float* eb = (const float*)d_in[4];
    float* out = (float*)d_out;
    char* ws = (char*)d_ws;

    // ws layout
    float* topk_w      = (float*)(ws + 0);                 // 256 KB
    int*   topk_e      = (int*)  (ws + 262144);            // 256 KB
    int*   counts      = (int*)  (ws + 524288);            // 8 ints
    int*   cursors     = (int*)  (ws + 524320);            // 8 ints  (contiguous w/ counts)
    int*   slot_token  = (int*)  (ws + 524416);            // 266240 B (S_PAD)
    float* slot_w      = (float*)(ws + 790656);            // 266240 B (S_PAD)
    int*   inv_slot    = (int*)  (ws + 1056896);           // 262144 B (S_TOT)
    float* partial     = (float*)(ws + 1319040);           // 6 MB  [KSPLIT][T][8] fp32
    unsigned short* WTb= (unsigned short*)(ws + 7610496);  // 3 MB bf16 W k-blocked
    unsigned short* xbf= (unsigned short*)(ws + 10756224); // 48 MB bf16 x
    float* routed      = (float*)(ws + 61087872);          // 68 MB routed outputs
    const size_t NEED_ROUTED = 61087872 + (size_t)S_PAD * D_OUT * 4;  // ~129 MB
    bool use_routed = (ws_size >= NEED_ROUTED);

    convw_kernel       <<<N_EXP * NKB, 256, 0, stream>>>(eW, WTb, counts);
    gate_partial_kernel<<<dim3(T_TOKENS / 64, KSPLIT), 64, 0, stream>>>(x, gW, xbf, partial);
    gate_final_kernel  <<<T_TOKENS / 256, 256, 0, stream>>>(partial, gb, topk_w, topk_e, counts);
    scatter_kernel     <<<S_TOT / (256 * 4), 256, 0, stream>>>(topk_e, topk_w, counts, cursors,
                                                               slot_token, slot_w, inv_slot);
    if (use_routed) {
        moe_gemm_kernel<true><<<S_PAD / 128, 256, 0, stream>>>(xbf, WTb, eb, counts,
                                                               slot_token, slot_w, routed);
        combine_kernel<<<T_TOKENS * D_OUT / 4 / 256, 256, 0, stream>>>(routed, inv_slot,
                                                                       topk_w, out);
    } else {
        // fallback: pads must be (token=0, w=0) for the atomic path
        hipMemsetAsync(slot_token, 0, 532480, stream);
        hipMemsetAsync(out, 0, (size_t)out_size * sizeof(float), stream);
        moe_gemm_kernel<false><<<S_PAD / 128, 256, 0, stream>>>(xbf, WTb, eb, counts,
                                                                slot_token, slot_w, out);
    }
}